// Round 1
// baseline (18362.549 us; speedup 1.0000x reference)
//
#include <hip/hip_runtime.h>

// ---------------- problem constants ----------------
#define NB 256     // batch
#define NT 512     // seq len
#define NI 128     // input size
#define NH 512     // hidden
#define NO 128     // output size
#define NGRP 16    // batch groups
#define RPG 16     // rows (batch) per group
#define BPG 8      // blocks per group (each owns 64 cols)

typedef __attribute__((ext_vector_type(8))) __bf16 bf16x8;
typedef __attribute__((ext_vector_type(4))) float  f32x4;

#define MFMA16(a,b,c) __builtin_amdgcn_mfma_f32_16x16x32_bf16((a),(b),(c),0,0,0)

// ---------------- LDS layout ----------------
// x tiles: double buffered [16 rows][128 bf16] = 4KB each
// h0 tiles: double buffered [16 rows][512 bf16] = 16KB each
// h1 tile: single buffer 16KB (reads and restage separated by barriers)
#define XSZ   (RPG*NI*2)          // 4096
#define HSZ   (RPG*NH*2)          // 16384
#define XOFF  0
#define H0OFF (2*XSZ)             // 8192
#define H1OFF (H0OFF + 2*HSZ)     // 40960
#define SMEM_BYTES (H1OFF + HSZ)  // 57344

__device__ __forceinline__ float fast_tanh(float x){
  x = fminf(15.f, fmaxf(-15.f, x));
  float e = __expf(2.f * x);
  return 1.f - 2.f / (e + 1.f);
}

__device__ __forceinline__ bf16x8 cvt8(float4 a, float4 b){
  bf16x8 r;
  r[0]=(__bf16)a.x; r[1]=(__bf16)a.y; r[2]=(__bf16)a.z; r[3]=(__bf16)a.w;
  r[4]=(__bf16)b.x; r[5]=(__bf16)b.y; r[6]=(__bf16)b.z; r[7]=(__bf16)b.w;
  return r;
}

// B-fragment: lane holds W[col = c][k0..k0+8) as bf16x8 (col = lane&15 handled by caller)
__device__ __forceinline__ bf16x8 loadWfrag(const float* __restrict__ W, int ldk, int row, int k0){
  const float4* p = (const float4*)(W + (size_t)row * ldk + k0);
  return cvt8(p[0], p[1]);
}

__global__ __launch_bounds__(256, 1)
void rnn_persistent(const float* __restrict__ x,
                    const float* __restrict__ hid,
                    const float* __restrict__ Wih0, const float* __restrict__ bih0,
                    const float* __restrict__ Whh0, const float* __restrict__ bhh0,
                    const float* __restrict__ Wih1, const float* __restrict__ bih1,
                    const float* __restrict__ Whh1, const float* __restrict__ bhh1,
                    const float* __restrict__ fcW,  const float* __restrict__ fcb,
                    float* __restrict__ out,
                    unsigned* __restrict__ flags,
                    __bf16* __restrict__ h0g, __bf16* __restrict__ h1g)
{
  __shared__ __align__(16) char smem[SMEM_BYTES];

  const int tid  = threadIdx.x;
  const int lane = tid & 63;
  const int wv   = tid >> 6;
  const int lr   = lane & 15;   // A-row / B-col / D-col lane index
  const int lq   = lane >> 4;   // k-group / D-row-group

  // block mapping: keep a group's 8 blocks on one XCD class (blockIdx % 8)
  const int bq  = blockIdx.x;
  const int j   = (bq >> 3) & 7;            // block-in-group: owns cols [j*64, j*64+64)
  const int g   = (bq & 7) + 8 * (bq >> 6); // group 0..15
  const int col = j * 64 + wv * 16 + lr;    // this lane's output column
  const int row0 = g * RPG;                 // group's first batch row

  // ---------------- weights -> registers (B-fragments) ----------------
  bf16x8 wih0[4], whh0[16], wih1[16], whh1[16];
#pragma unroll
  for (int kt = 0; kt < 4;  ++kt) wih0[kt] = loadWfrag(Wih0, NI, col, kt*32 + lq*8);
#pragma unroll
  for (int kt = 0; kt < 16; ++kt) whh0[kt] = loadWfrag(Whh0, NH, col, kt*32 + lq*8);
#pragma unroll
  for (int kt = 0; kt < 16; ++kt) wih1[kt] = loadWfrag(Wih1, NH, col, kt*32 + lq*8);
#pragma unroll
  for (int kt = 0; kt < 16; ++kt) whh1[kt] = loadWfrag(Whh1, NH, col, kt*32 + lq*8);
  const float bias0 = bih0[col] + bhh0[col];
  const float bias1 = bih1[col] + bhh1[col];

  unsigned* cnt = flags + g * 16;  // one counter per group, own cache line

  // ---------------- prologue staging ----------------
  { // x_0 -> X[0]
    int r = tid >> 4, i0 = (tid & 15) * 8;
    const float4* xp = (const float4*)(x + ((size_t)(row0 + r) * NT + 0) * NI + i0);
    bf16x8 v = cvt8(xp[0], xp[1]);
    int o = r * 256 + i0 * 2;
    *(bf16x8*)(smem + XOFF + (o ^ ((r & 7) << 4))) = v;
  }
#pragma unroll
  for (int it = 0; it < 4; ++it) { // hidden[0]->h0A(region0), hidden[1]->h1A
    int e = it * 2048 + tid * 8;
    int r = e >> 9, c = e & 511;
    int o = r * 1024 + c * 2;
    const float4* hp0 = (const float4*)(hid + (size_t)(row0 + r) * NH + c);
    *(bf16x8*)(smem + H0OFF + (o ^ ((r & 7) << 4))) = cvt8(hp0[0], hp0[1]);
    const float4* hp1 = (const float4*)(hid + (size_t)NB * NH + (size_t)(row0 + r) * NH + c);
    *(bf16x8*)(smem + H1OFF + (o ^ ((r & 7) << 4))) = cvt8(hp1[0], hp1[1]);
  }
  __syncthreads();

  unsigned target = 0;
  const int akb = lq * 16;  // A-frag k-byte offset within a 64B k-tile row chunk

  for (int t = 0; t < NT; ++t) {
    const char* xA  = smem + XOFF  + (t & 1) * XSZ;
    const char* h0A = smem + H0OFF + (t & 1) * HSZ;
    char*       h0N = smem + H0OFF + ((t & 1) ^ 1) * HSZ;
    char*       h1A = smem + H1OFF;

    // ---- layer 0: acc = x_t @ Wih0^T + h0 @ Whh0^T ----
    f32x4 a0 = {0.f,0.f,0.f,0.f}, a1 = {0.f,0.f,0.f,0.f};
#pragma unroll
    for (int kt = 0; kt < 4; ++kt) {
      bf16x8 a = *(const bf16x8*)(xA + lr * 256 + ((kt * 64 + akb) ^ ((lr & 7) << 4)));
      a0 = MFMA16(a, wih0[kt], a0);
    }
#pragma unroll
    for (int kt = 0; kt < 16; ++kt) {
      bf16x8 a = *(const bf16x8*)(h0A + lr * 1024 + ((kt * 64 + akb) ^ ((lr & 7) << 4)));
      if (kt & 1) a1 = MFMA16(a, whh0[kt], a1); else a0 = MFMA16(a, whh0[kt], a0);
    }

    const size_t slab = ((size_t)(t & 1) * NGRP + g) * (RPG * NH);
#pragma unroll
    for (int jj = 0; jj < 4; ++jj) {
      int r = lq * 4 + jj;
      float v = fast_tanh(a0[jj] + a1[jj] + bias0);
      h0g[slab + r * NH + col] = (__bf16)v;
      if (t == NT - 1) out[NB * NO + (row0 + r) * NH + col] = v;  // new_hidden[0]
    }
    __threadfence();
    if (lane == 0)
      __hip_atomic_fetch_add(cnt, 1u, __ATOMIC_RELEASE, __HIP_MEMORY_SCOPE_AGENT);
    target += 32;  // 8 blocks * 4 waves

    // ---- layer 1 recurrent part (independent of bar1) hides the spin ----
    f32x4 c0 = {0.f,0.f,0.f,0.f}, c1 = {0.f,0.f,0.f,0.f};
#pragma unroll
    for (int kt = 0; kt < 16; ++kt) {
      bf16x8 a = *(const bf16x8*)(h1A + lr * 1024 + ((kt * 64 + akb) ^ ((lr & 7) << 4)));
      if (kt & 1) c1 = MFMA16(a, whh1[kt], c1); else c0 = MFMA16(a, whh1[kt], c0);
    }
    // prefetch x_{t+1} into the other x buffer (independent)
    if (t + 1 < NT) {
      int r = tid >> 4, i0 = (tid & 15) * 8;
      const float4* xp = (const float4*)(x + ((size_t)(row0 + r) * NT + (t + 1)) * NI + i0);
      bf16x8 v = cvt8(xp[0], xp[1]);
      char* dst = smem + XOFF + ((t & 1) ^ 1) * XSZ;
      *(bf16x8*)(dst + ((r * 256 + i0 * 2) ^ ((r & 7) << 4))) = v;
    }

    // ---- bar1: wait for full h0(t), stage into h0N ----
    if (tid == 0) {
      while ((int)(__hip_atomic_load(cnt, __ATOMIC_ACQUIRE, __HIP_MEMORY_SCOPE_AGENT) - target) < 0) {}
    }
    __syncthreads();
#pragma unroll
    for (int it = 0; it < 4; ++it) {
      int o = it * 4096 + tid * 16;
      bf16x8 v = *(const bf16x8*)((const char*)h0g + slab * 2 + o);
      *(bf16x8*)(h0N + (o ^ (((o >> 10) & 7) << 4))) = v;
    }
    __syncthreads();

    // ---- layer 1 input-projection part: h0(t) @ Wih1^T ----
#pragma unroll
    for (int kt = 0; kt < 16; ++kt) {
      bf16x8 a = *(const bf16x8*)(h0N + lr * 1024 + ((kt * 64 + akb) ^ ((lr & 7) << 4)));
      if (kt & 1) c1 = MFMA16(a, wih1[kt], c1); else c0 = MFMA16(a, wih1[kt], c0);
    }
#pragma unroll
    for (int jj = 0; jj < 4; ++jj) {
      int r = lq * 4 + jj;
      float v = fast_tanh(c0[jj] + c1[jj] + bias1);
      h1g[slab + r * NH + col] = (__bf16)v;
      if (t == NT - 1) out[NB * NO + NB * NH + (row0 + r) * NH + col] = v;  // new_hidden[1]
    }
    __threadfence();
    if (lane == 0)
      __hip_atomic_fetch_add(cnt, 1u, __ATOMIC_RELEASE, __HIP_MEMORY_SCOPE_AGENT);
    target += 32;

    // ---- bar2: wait for full h1(t), restage h1A for next step ----
    if (tid == 0) {
      while ((int)(__hip_atomic_load(cnt, __ATOMIC_ACQUIRE, __HIP_MEMORY_SCOPE_AGENT) - target) < 0) {}
    }
    __syncthreads();
#pragma unroll
    for (int it = 0; it < 4; ++it) {
      int o = it * 4096 + tid * 16;
      bf16x8 v = *(const bf16x8*)((const char*)h1g + slab * 2 + o);
      *(bf16x8*)(h1A + (o ^ (((o >> 10) & 7) << 4))) = v;
    }
    __syncthreads();
  }

  // ---------------- FC epilogue: out = h1(T) @ fcW^T + fcb ----------------
  if (wv == 0) {
    f32x4 acc = {0.f,0.f,0.f,0.f};
#pragma unroll
    for (int kt = 0; kt < 16; ++kt) {
      bf16x8 a = *(const bf16x8*)(smem + H1OFF + lr * 1024 + ((kt * 64 + akb) ^ ((lr & 7) << 4)));
      bf16x8 b = loadWfrag(fcW, NH, j * 16 + lr, kt * 32 + lq * 8);
      acc = MFMA16(a, b, acc);
    }
    float fb = fcb[j * 16 + lr];
#pragma unroll
    for (int jj = 0; jj < 4; ++jj) {
      int r = lq * 4 + jj;
      out[(row0 + r) * NO + j * 16 + lr] = acc[jj] + fb;
    }
  }
}

extern "C" void kernel_launch(void* const* d_in, const int* in_sizes, int n_in,
                              void* d_out, int out_size, void* d_ws, size_t ws_size,
                              hipStream_t stream)
{
  const float* x    = (const float*)d_in[0];
  const float* hid  = (const float*)d_in[1];
  const float* Wih0 = (const float*)d_in[2];
  const float* bih0 = (const float*)d_in[3];
  const float* Whh0 = (const float*)d_in[4];
  const float* bhh0 = (const float*)d_in[5];
  const float* Wih1 = (const float*)d_in[6];
  const float* bih1 = (const float*)d_in[7];
  const float* Whh1 = (const float*)d_in[8];
  const float* bhh1 = (const float*)d_in[9];
  const float* fcW  = (const float*)d_in[10];
  const float* fcb  = (const float*)d_in[11];
  float* out = (float*)d_out;

  unsigned* flags = (unsigned*)d_ws;
  __bf16* h0g = (__bf16*)((char*)d_ws + 4096);
  __bf16* h1g = (__bf16*)((char*)d_ws + 4096 + (size_t)2 * NGRP * RPG * NH * 2);

  // zero the barrier counters every launch (ws is poisoned, never re-poisoned)
  (void)hipMemsetAsync(d_ws, 0, 4096, stream);

  hipLaunchKernelGGL(rnn_persistent, dim3(NGRP * BPG), dim3(256), 0, stream,
                     x, hid, Wih0, bih0, Whh0, bhh0, Wih1, bih1, Whh1, bhh1,
                     fcW, fcb, out, flags, h0g, h1g);
}

// Round 2
// 2391.318 us; speedup vs baseline: 7.6788x; 7.6788x over previous
//
#include <hip/hip_runtime.h>

// ---------------- problem constants ----------------
#define NB 256     // batch
#define NT 512     // seq len
#define NI 128     // input size
#define NH 512     // hidden
#define NO 128     // output size
#define NGRP 16    // batch groups
#define RPG 16     // rows (batch) per group
#define BPG 8      // blocks per group (each owns 64 cols)

typedef __attribute__((ext_vector_type(8))) __bf16 bf16x8;
typedef __attribute__((ext_vector_type(4))) float  f32x4;
typedef unsigned long long u64;

#define MFMA16(a,b,c) __builtin_amdgcn_mfma_f32_16x16x32_bf16((a),(b),(c),0,0,0)

// ---------------- LDS layout ----------------
// x: double buffered [16][128] bf16 = 4KB each
// h0: single [16][512] bf16 = 16KB (restage is barrier-separated from reads)
// h1: single 16KB
#define XSZ   (RPG*NI*2)           // 4096
#define HSZ   (RPG*NH*2)           // 16384
#define XOFF  0
#define H0OFF (2*XSZ)              // 8192
#define H1OFF (H0OFF + HSZ)        // 24576
#define SMEM_BYTES (H1OFF + HSZ)   // 40960

__device__ __forceinline__ float fast_tanh(float x){
  x = fminf(15.f, fmaxf(-15.f, x));
  float e = __expf(2.f * x);
  return 1.f - 2.f / (e + 1.f);
}

__device__ __forceinline__ bf16x8 cvt8(float4 a, float4 b){
  bf16x8 r;
  r[0]=(__bf16)a.x; r[1]=(__bf16)a.y; r[2]=(__bf16)a.z; r[3]=(__bf16)a.w;
  r[4]=(__bf16)b.x; r[5]=(__bf16)b.y; r[6]=(__bf16)b.z; r[7]=(__bf16)b.w;
  return r;
}

// W fragment: lane holds W[row][k0..k0+8) as bf16x8 (used as MFMA A operand)
__device__ __forceinline__ bf16x8 loadWfrag(const float* __restrict__ W, int ldk, int row, int k0){
  const float4* p = (const float4*)(W + (size_t)row * ldk + k0);
  return cvt8(p[0], p[1]);
}

// coherence-point (L3) data movement: relaxed agent atomics -> sc-flagged, L2-bypassing
__device__ __forceinline__ void st_u64(u64* p, u64 v){
  __hip_atomic_store(p, v, __ATOMIC_RELAXED, __HIP_MEMORY_SCOPE_AGENT);
}
__device__ __forceinline__ u64 ld_u64(const u64* p){
  return __hip_atomic_load(p, __ATOMIC_RELAXED, __HIP_MEMORY_SCOPE_AGENT);
}
__device__ __forceinline__ unsigned ld_u32(const unsigned* p){
  return __hip_atomic_load(p, __ATOMIC_RELAXED, __HIP_MEMORY_SCOPE_AGENT);
}

__device__ __forceinline__ u64 pack4bf(f32x4 v){
  union { __bf16 h[4]; u64 u; } un;
  un.h[0]=(__bf16)v[0]; un.h[1]=(__bf16)v[1]; un.h[2]=(__bf16)v[2]; un.h[3]=(__bf16)v[3];
  return un.u;
}

__global__ __launch_bounds__(256, 1)
void rnn_persistent(const float* __restrict__ x,
                    const float* __restrict__ hid,
                    const float* __restrict__ Wih0, const float* __restrict__ bih0,
                    const float* __restrict__ Whh0, const float* __restrict__ bhh0,
                    const float* __restrict__ Wih1, const float* __restrict__ bih1,
                    const float* __restrict__ Whh1, const float* __restrict__ bhh1,
                    const float* __restrict__ fcW,  const float* __restrict__ fcb,
                    float* __restrict__ out,
                    unsigned* __restrict__ flags,
                    __bf16* __restrict__ h0g, __bf16* __restrict__ h1g)
{
  __shared__ __align__(16) char smem[SMEM_BYTES];

  const int tid  = threadIdx.x;
  const int lane = tid & 63;
  const int wv   = tid >> 6;
  const int lr   = lane & 15;   // batch row (D col after operand swap)
  const int lq   = lane >> 4;   // k-chunk on load; D row-group on output

  const int bq  = blockIdx.x;
  const int j   = (bq >> 3) & 7;            // block-in-group: owns cols [j*64, j*64+64)
  const int g   = (bq & 7) + 8 * (bq >> 6); // group 0..15
  const int cb  = j * 64 + wv * 16;         // wave's 16-col tile base
  const int row0 = g * RPG;

  // ---------------- weights -> registers (as MFMA A operands) ----------------
  bf16x8 wih0[4], whh0[16], wih1[16], whh1[16];
#pragma unroll
  for (int kt = 0; kt < 4;  ++kt) wih0[kt] = loadWfrag(Wih0, NI, cb + lr, kt*32 + lq*8);
#pragma unroll
  for (int kt = 0; kt < 16; ++kt) whh0[kt] = loadWfrag(Whh0, NH, cb + lr, kt*32 + lq*8);
#pragma unroll
  for (int kt = 0; kt < 16; ++kt) wih1[kt] = loadWfrag(Wih1, NH, cb + lr, kt*32 + lq*8);
#pragma unroll
  for (int kt = 0; kt < 16; ++kt) whh1[kt] = loadWfrag(Whh1, NH, cb + lr, kt*32 + lq*8);

  // per-lane 4-col bias vectors (cols cb+lq*4 .. +3)
  const f32x4 bias0 = *(const f32x4*)(bih0 + cb + lq*4) + *(const f32x4*)(bhh0 + cb + lq*4);
  const f32x4 bias1 = *(const f32x4*)(bih1 + cb + lq*4) + *(const f32x4*)(bhh1 + cb + lq*4);

  unsigned* cnt = flags + g * 32;  // one counter per group, own cache line
  u64* h0u = (u64*)h0g;
  u64* h1u = (u64*)h1g;

  // ---------------- prologue staging ----------------
  { // x_0 -> X[0]
    int r = tid >> 4, i0 = (tid & 15) * 8;
    const float4* xp = (const float4*)(x + ((size_t)(row0 + r) * NT + 0) * NI + i0);
    bf16x8 v = cvt8(xp[0], xp[1]);
    int o = r * 256 + i0 * 2;
    *(bf16x8*)(smem + XOFF + (o ^ ((r & 7) << 4))) = v;
  }
#pragma unroll
  for (int it = 0; it < 4; ++it) { // hidden[0]->h0L, hidden[1]->h1L
    int e = it * 2048 + tid * 8;
    int r = e >> 9, c = e & 511;
    int o = r * 1024 + c * 2;
    const float4* hp0 = (const float4*)(hid + (size_t)(row0 + r) * NH + c);
    *(bf16x8*)(smem + H0OFF + (o ^ ((r & 7) << 4))) = cvt8(hp0[0], hp0[1]);
    const float4* hp1 = (const float4*)(hid + (size_t)NB * NH + (size_t)(row0 + r) * NH + c);
    *(bf16x8*)(smem + H1OFF + (o ^ ((r & 7) << 4))) = cvt8(hp1[0], hp1[1]);
  }
  __syncthreads();

  unsigned target = 0;

#define HFRAG(base, kt) (*(const bf16x8*)((base) + lr * 1024 + (((kt) * 64 + lq * 16) ^ ((lr & 7) << 4))))

  // tick t: compute h0(t) [if t<NT] and h1(t-1) [if t>0]; one group barrier per tick
  for (int t = 0; t <= NT; ++t) {
    const char* xA  = smem + XOFF + (t & 1) * XSZ;
    const char* h0L = smem + H0OFF;   // holds h0(t-1)
    const char* h1L = smem + H1OFF;   // holds h1(t-2)
    const bool do0 = (t < NT), do1 = (t > 0);

    f32x4 a0 = {0.f,0.f,0.f,0.f}, a1 = {0.f,0.f,0.f,0.f};
    f32x4 c0 = {0.f,0.f,0.f,0.f}, c1 = {0.f,0.f,0.f,0.f};

    if (do0) {
#pragma unroll
      for (int kt = 0; kt < 4; ++kt) {
        bf16x8 a = *(const bf16x8*)(xA + lr * 256 + ((kt * 64 + lq * 16) ^ ((lr & 7) << 4)));
        a0 = MFMA16(wih0[kt], a, a0);
      }
#pragma unroll
      for (int kt = 0; kt < 16; ++kt) {
        bf16x8 a = HFRAG(h0L, kt);
        if (kt & 1) a1 = MFMA16(whh0[kt], a, a1); else a0 = MFMA16(whh0[kt], a, a0);
      }
    }
    if (do1) {
#pragma unroll
      for (int kt = 0; kt < 16; ++kt) {
        bf16x8 a = HFRAG(h0L, kt);   // h0(t-1), same staged buffer as layer 0
        if (kt & 1) c1 = MFMA16(wih1[kt], a, c1); else c0 = MFMA16(wih1[kt], a, c0);
      }
#pragma unroll
      for (int kt = 0; kt < 16; ++kt) {
        bf16x8 a = HFRAG(h1L, kt);   // h1(t-2)
        if (kt & 1) c1 = MFMA16(whh1[kt], a, c1); else c0 = MFMA16(whh1[kt], a, c0);
      }
    }

    // prefetch x(t+1) into the inactive x buffer (independent of the barrier)
    if (t + 1 < NT) {
      int r = tid >> 4, i0 = (tid & 15) * 8;
      const float4* xp = (const float4*)(x + ((size_t)(row0 + r) * NT + (t + 1)) * NI + i0);
      bf16x8 v = cvt8(xp[0], xp[1]);
      char* dst = smem + XOFF + ((t + 1) & 1) * XSZ;
      *(bf16x8*)(dst + ((r * 256 + i0 * 2) ^ ((r & 7) << 4))) = v;
    }

    // ---- publish (lane holds 4 consecutive cols of batch row lr) ----
    const size_t sl = ((size_t)(t & 1) * NGRP + g) * (RPG * NH);
    if (do0) {
      f32x4 s = a0 + a1 + bias0;
      f32x4 h; h[0]=fast_tanh(s[0]); h[1]=fast_tanh(s[1]); h[2]=fast_tanh(s[2]); h[3]=fast_tanh(s[3]);
      if (t == NT - 1)
        *(f32x4*)(out + NB * NO + (size_t)(row0 + lr) * NH + cb + lq * 4) = h;  // new_hidden[0]
      st_u64(h0u + ((sl + (size_t)lr * NH + cb + lq * 4) >> 2), pack4bf(h));
    }
    if (do1) {
      f32x4 s = c0 + c1 + bias1;
      f32x4 h; h[0]=fast_tanh(s[0]); h[1]=fast_tanh(s[1]); h[2]=fast_tanh(s[2]); h[3]=fast_tanh(s[3]);
      if (t == NT)
        *(f32x4*)(out + NB * NO + (size_t)NB * NH + (size_t)(row0 + lr) * NH + cb + lq * 4) = h;  // new_hidden[1]
      st_u64(h1u + ((sl + (size_t)lr * NH + cb + lq * 4) >> 2), pack4bf(h));
    }

    // release-by-drain: wave's stores reached the coherence point before the flag bump
    asm volatile("s_waitcnt vmcnt(0)" ::: "memory");
    if (lane == 0)
      __hip_atomic_fetch_add(cnt, 1u, __ATOMIC_RELAXED, __HIP_MEMORY_SCOPE_AGENT);
    target += 32;  // 8 blocks * 4 waves per tick

    if (tid == 0) {
      while ((int)(ld_u32(cnt) - target) < 0) {}
    }
    __syncthreads();

    // ---- restage published h into LDS (L2-bypassing loads from the slabs) ----
    u64 v0[8], v1[8];
    if (do0) {
#pragma unroll
      for (int it = 0; it < 8; ++it) v0[it] = ld_u64(h0u + (sl >> 2) + it * 256 + tid);
    }
    if (do1) {
#pragma unroll
      for (int it = 0; it < 8; ++it) v1[it] = ld_u64(h1u + (sl >> 2) + it * 256 + tid);
    }
    if (do0) {
#pragma unroll
      for (int it = 0; it < 8; ++it) {
        int o = (it * 256 + tid) * 8, r = o >> 10;
        *(u64*)(smem + H0OFF + (o ^ ((r & 7) << 4))) = v0[it];
      }
    }
    if (do1) {
#pragma unroll
      for (int it = 0; it < 8; ++it) {
        int o = (it * 256 + tid) * 8, r = o >> 10;
        *(u64*)(smem + H1OFF + (o ^ ((r & 7) << 4))) = v1[it];
      }
    }
    __syncthreads();
  }

  // ---------------- FC epilogue: out = h1(T-1) @ fcW^T + fcb ----------------
  if (wv == 0) {
    f32x4 acc = {0.f,0.f,0.f,0.f};
#pragma unroll
    for (int kt = 0; kt < 16; ++kt) {
      bf16x8 b = HFRAG(smem + H1OFF, kt);
      bf16x8 a = loadWfrag(fcW, NH, j * 16 + lr, kt * 32 + lq * 8);
      acc = MFMA16(a, b, acc);
    }
    f32x4 fb = *(const f32x4*)(fcb + j * 16 + lq * 4);
    *(f32x4*)(out + (size_t)(row0 + lr) * NO + j * 16 + lq * 4) = acc + fb;
  }
#undef HFRAG
}

extern "C" void kernel_launch(void* const* d_in, const int* in_sizes, int n_in,
                              void* d_out, int out_size, void* d_ws, size_t ws_size,
                              hipStream_t stream)
{
  const float* x    = (const float*)d_in[0];
  const float* hid  = (const float*)d_in[1];
  const float* Wih0 = (const float*)d_in[2];
  const float* bih0 = (const float*)d_in[3];
  const float* Whh0 = (const float*)d_in[4];
  const float* bhh0 = (const float*)d_in[5];
  const float* Wih1 = (const float*)d_in[6];
  const float* bih1 = (const float*)d_in[7];
  const float* Whh1 = (const float*)d_in[8];
  const float* bhh1 = (const float*)d_in[9];
  const float* fcW  = (const float*)d_in[10];
  const float* fcb  = (const float*)d_in[11];
  float* out = (float*)d_out;

  unsigned* flags = (unsigned*)d_ws;
  __bf16* h0g = (__bf16*)((char*)d_ws + 4096);
  __bf16* h1g = (__bf16*)((char*)d_ws + 4096 + (size_t)2 * NGRP * RPG * NH * 2);

  // zero the barrier counters every launch (ws is poisoned, never re-poisoned)
  (void)hipMemsetAsync(d_ws, 0, 4096, stream);

  hipLaunchKernelGGL(rnn_persistent, dim3(NGRP * BPG), dim3(256), 0, stream,
                     x, hid, Wih0, bih0, Whh0, bhh0, Wih1, bih1, Whh1, bhh1,
                     fcW, fcb, out, flags, h0g, h1g);
}